// Round 2
// baseline (285.360 us; speedup 1.0000x reference)
//
#include <hip/hip_runtime.h>
#include <stdint.h>

typedef float f32x4 __attribute__((ext_vector_type(4)));
typedef __bf16 bf16x8 __attribute__((ext_vector_type(8)));
typedef unsigned short ushortx8 __attribute__((ext_vector_type(8)));

#define D_DIM 512
#define KGC 10
#define NCLU 8
#define BATCH 32
#define WPOS 250
#define WPAD 256
#define KDIM 3584   // 512*7
#define MROWS 522   // 512 feat + 10 assign
#define MPAD 528    // Y rows per batch
#define MBIG 640    // padded W rows (4 x 160)
#define BM 160      // block m-tile
#define BN 64       // block n-tile
#define NS 56       // K steps (3584 / 64)
#define NTB 128     // n-tiles (8192 / 64)
#define MSB 4       // m-slices (640 / 160)

__device__ __forceinline__ float bf2f(unsigned short u) {
  union { unsigned int i; float f; } v; v.i = ((unsigned int)u) << 16; return v.f;
}
__device__ __forceinline__ unsigned short f2bf(float f) {
  union { float f; unsigned int i; } v; v.f = f;
  unsigned int r = v.i + 0x7FFFu + ((v.i >> 16) & 1u);
  return (unsigned short)(r >> 16);
}

__device__ __forceinline__ void load_lds16(const void* g, void* l) {
  __builtin_amdgcn_global_load_lds(
      (const __attribute__((address_space(1))) void*)g,
      (__attribute__((address_space(3))) void*)l, 16, 0, 0);
}

// ---------------- prep: Wcat(bf16) rows 0..639 = [feat_w ; assign_w ; zeros], bcat fp32 ----------------
__global__ void prep_kernel(const float* __restrict__ fw,
                            const float* __restrict__ fb,
                            const float* __restrict__ aw,
                            const float* __restrict__ ab,
                            unsigned short* __restrict__ Wcat,
                            float* __restrict__ bcat) {
  int r = blockIdx.x;
  unsigned short* dst = Wcat + (size_t)r * KDIM;
  const float* src = (r < D_DIM) ? (fw + (size_t)r * KDIM)
                   : (r < MROWS) ? (aw + (size_t)(r - D_DIM) * KDIM)
                                 : nullptr;
  for (int i = threadIdx.x; i < KDIM / 4; i += 256) {
    unsigned short o0 = 0, o1 = 0, o2 = 0, o3 = 0;
    if (src) {
      float4 v = ((const float4*)src)[i];
      o0 = f2bf(v.x); o1 = f2bf(v.y); o2 = f2bf(v.z); o3 = f2bf(v.w);
    }
    ushort4 o; o.x = o0; o.y = o1; o.z = o2; o.w = o3;
    ((ushort4*)dst)[i] = o;
  }
  if (threadIdx.x == 0)
    bcat[r] = r < D_DIM ? fb[r] : (r < MROWS ? ab[r - D_DIM] : 0.f);
}

// ---------------- fused full-K GEMM: Y[b][m][w](bf16) = relu_if_feat(W @ x + bias) ----------------
// 256 thr (4 waves 2m x 2n, wave tile 80x32), grid 512 = 2 blocks/CU.
// DOUBLE-BUFFERED, 1 barrier/step: stage(next) issued BEFORE compute(cur); the
// vmcnt(0)+lgkmcnt(0) drain inside __syncthreads sits AFTER ~1.3K cyc of
// ds_read+MFMA, so staging latency is hidden (T3 minimum-2-phase recipe).
__global__ __launch_bounds__(256, 2) void gemm_fused(
    const float* __restrict__ x, const unsigned short* __restrict__ Wcat,
    const float* __restrict__ bcat, unsigned short* __restrict__ Y) {
  __shared__ __align__(16) unsigned short Wl[2][BM * 64];   // 2 x 20,480 B swizzled
  __shared__ __align__(16) unsigned short Xl[2][BN * 64];   // 2 x  8,192 B swizzled
  const int tid = threadIdx.x;
  // XCD-bijective swizzle (512 = 8 XCD x 64): ms fastest within a chunk so the
  // 4 ms-blocks sharing an x n-chunk land on the same XCD -> x reuse hits that L2.
  const int hw = blockIdx.x;
  const int work = (hw & 7) * 64 + (hw >> 3);
  const int nt = work >> 2, ms = work & 3;
  const int lane = tid & 63, wv = tid >> 6;     // 4 waves
  const int wm = wv >> 1, wn = wv & 1;          // 2m x 2n
  const int fr = lane & 15, kg = lane >> 4;
  const int sx = fr & 7;
  const int nloc = tid & 63, oc = tid >> 6;     // staging: col nloc, octets oc & oc+4
  const int nglob = nt * BN + nloc;
  const int b = nglob >> 8, ncol = nglob & 255;
  const bool okn = ncol < WPOS;
  const float* xb = x + (size_t)b * KDIM * WPOS + ncol;
  const unsigned short* Wg = Wcat + (size_t)ms * BM * KDIM;

  float xr[16];
  auto loadx = [&](int st) {
#pragma unroll
    for (int pass = 0; pass < 2; pass++) {
      int k0 = st * 64 + (oc + 4 * pass) * 8;
#pragma unroll
      for (int e = 0; e < 8; e++)
        xr[pass * 8 + e] = okn ? xb[(size_t)(k0 + e) * WPOS] : 0.f;
    }
  };
  // W lds-dma: 160 rows x 8 octets = 1280 slots, exactly 5 per thread.
  // LDS dest linear per-lane (+16B/lane matches HW); global source pre-swizzled.
  auto stageW = [&](int st, int buf) {
#pragma unroll
    for (int it = 0; it < 5; it++) {
      int s = it * 256 + tid;
      int row = s >> 3, p = s & 7;
      int blk = p ^ (row & 7);
      load_lds16(Wg + (size_t)row * KDIM + st * 64 + blk * 8, &Wl[buf][s * 8]);
    }
  };
  auto writeX = [&](int buf) {
#pragma unroll
    for (int pass = 0; pass < 2; pass++) {
      int oct = oc + 4 * pass;
      ushortx8 pk;
#pragma unroll
      for (int e = 0; e < 8; e++) pk[e] = f2bf(xr[pass * 8 + e]);
      *(ushortx8*)&Xl[buf][nloc * 64 + (oct ^ (nloc & 7)) * 8] = pk;
    }
  };

  f32x4 acc[5][2];
  const f32x4 zero = {0.f, 0.f, 0.f, 0.f};
#pragma unroll
  for (int f = 0; f < 5; f++) { acc[f][0] = zero; acc[f][1] = zero; }

  // prologue: fill buf0, prefetch x(1)
  stageW(0, 0);
  loadx(0);
  writeX(0);          // compiler waits on xr automatically
  loadx(1);
  __syncthreads();    // drains dma into Wl[0] (vmcnt) + X writes (lgkm)

  for (int st = 0; st < NS; st++) {
    const int cur = st & 1, nxt = cur ^ 1;
    if (st + 1 < NS) {
      stageW(st + 1, nxt);   // dma -> Wl[nxt] (latency hidden under compute)
      writeX(nxt);           // xr holds x(st+1)
    }
    if (st + 2 < NS) loadx(st + 2);  // issue early; lands during compute
#pragma unroll
    for (int ks = 0; ks < 2; ks++) {
      const int off = ((ks * 4 + kg) ^ sx) * 8;
      bf16x8 b0 = *(const bf16x8*)&Xl[cur][(wn * 32 + fr) * 64 + off];
      bf16x8 b1 = *(const bf16x8*)&Xl[cur][(wn * 32 + 16 + fr) * 64 + off];
#pragma unroll
      for (int f = 0; f < 5; f++) {
        bf16x8 af = *(const bf16x8*)&Wl[cur][(wm * 80 + f * 16 + fr) * 64 + off];
        acc[f][0] = __builtin_amdgcn_mfma_f32_16x16x32_bf16(af, b0, acc[f][0], 0, 0, 0);
        acc[f][1] = __builtin_amdgcn_mfma_f32_16x16x32_bf16(af, b1, acc[f][1], 0, 0, 0);
      }
    }
    __syncthreads();  // single barrier/step: drains next-buf staging AFTER compute
  }

  // fused epilogue: C/D frag col = lane&15 (n), row = kg*4 + r (m within frag)
  const int bb = (nt * BN) >> 8;            // batch (all 64 block cols in same batch)
  const int cbase = (nt * BN) & 255;
  unsigned short* Yb = Y + (size_t)bb * MPAD * WPAD;
#pragma unroll
  for (int f = 0; f < 5; f++) {
    const int m0 = ms * BM + wm * 80 + f * 16 + kg * 4;
#pragma unroll
    for (int nf = 0; nf < 2; nf++) {
      const int c = cbase + wn * 32 + nf * 16 + fr;
#pragma unroll
      for (int r = 0; r < 4; r++) {
        const int m = m0 + r;
        if (m < MPAD) {
          float v = acc[f][nf][r] + bcat[m];
          if (m < D_DIM) v = fmaxf(v, 0.f);
          Yb[(size_t)m * WPAD + c] = f2bf(v);
        }
      }
    }
  }
}

// ---------------- epilogue: softmax, agg, subtract centroids*s_sum, L2-normalize ----------------
// 512 thr (8 waves, 1 d-row per thread), float4 broadcast soft reads,
// 8 independent accumulators to break the fma dependency chain.
__global__ __launch_bounds__(512) void epi_kernel(
    const unsigned short* __restrict__ Y, const float* __restrict__ cent,
    float* __restrict__ out) {
  __shared__ float soft[WPAD];
  __shared__ float red[8];
  const int b = blockIdx.x >> 3, k = blockIdx.x & 7;
  const int tid = threadIdx.x;
  const unsigned short* Yb = Y + (size_t)b * MPAD * WPAD;

  float sv = 0.f;
  if (tid < WPOS) {
    float lg[KGC];
    float mx = -1e30f;
#pragma unroll
    for (int j = 0; j < KGC; j++) {
      lg[j] = bf2f(Yb[(size_t)(D_DIM + j) * WPAD + tid]);
      mx = fmaxf(mx, lg[j]);
    }
    float s = 0.f, ek = 0.f;
#pragma unroll
    for (int j = 0; j < KGC; j++) {
      float e = __expf(lg[j] - mx);
      s += e;
      if (j == k) ek = e;
    }
    sv = ek / s;
  }
  if (tid < WPAD) soft[tid] = sv;   // tids 250..255 write 0
  __syncthreads();

  float v = sv;
#pragma unroll
  for (int o = 32; o > 0; o >>= 1) v += __shfl_down(v, o, 64);
  if ((tid & 63) == 0) red[tid >> 6] = v;
  __syncthreads();
  float ssum = 0.f;
#pragma unroll
  for (int i = 0; i < 8; i++) ssum += red[i];

  float a[8];
#pragma unroll
  for (int u = 0; u < 8; u++) a[u] = 0.f;
  const unsigned short* row = Yb + (size_t)tid * WPAD;
  for (int w = 0; w < WPAD; w += 8) {
    ushortx8 f0 = *(const ushortx8*)(row + w);
    float4 s0 = *(const float4*)&soft[w];
    float4 s1 = *(const float4*)&soft[w + 4];
    a[0] += bf2f(f0[0]) * s0.x;
    a[1] += bf2f(f0[1]) * s0.y;
    a[2] += bf2f(f0[2]) * s0.z;
    a[3] += bf2f(f0[3]) * s0.w;
    a[4] += bf2f(f0[4]) * s1.x;
    a[5] += bf2f(f0[5]) * s1.y;
    a[6] += bf2f(f0[6]) * s1.z;
    a[7] += bf2f(f0[7]) * s1.w;
  }
  float asum = ((a[0] + a[1]) + (a[2] + a[3])) + ((a[4] + a[5]) + (a[6] + a[7]));
  float c = asum - cent[(size_t)tid * KGC + k] * ssum;

  __syncthreads();
  float q = c * c;
#pragma unroll
  for (int o = 32; o > 0; o >>= 1) q += __shfl_down(q, o, 64);
  if ((tid & 63) == 0) red[tid >> 6] = q;
  __syncthreads();
  float nsum = 0.f;
#pragma unroll
  for (int i = 0; i < 8; i++) nsum += red[i];
  float norm = sqrtf(nsum);
  float inv = 1.f / fmaxf(norm, 1e-12f);

  float* ob = out + (size_t)b * (NCLU * D_DIM) + (size_t)k * D_DIM;
  ob[tid] = c * inv;
}

extern "C" void kernel_launch(void* const* d_in, const int* in_sizes, int n_in,
                              void* d_out, int out_size, void* d_ws, size_t ws_size,
                              hipStream_t stream) {
  const float* x  = (const float*)d_in[0];
  const float* fw = (const float*)d_in[1];
  const float* fb = (const float*)d_in[2];
  const float* aw = (const float*)d_in[3];
  const float* ab = (const float*)d_in[4];
  const float* ce = (const float*)d_in[5];
  float* out = (float*)d_out;
  char* ws = (char*)d_ws;

  const size_t WC_BYTES = (size_t)MBIG * KDIM * 2;   // 4,587,520
  const size_t BC_BYTES = 4096;
  unsigned short* Wc = (unsigned short*)(ws);
  float*          bc = (float*)(ws + WC_BYTES);
  unsigned short* Yv = (unsigned short*)(ws + WC_BYTES + BC_BYTES);
  // total ws use ~13.3 MB (Y = 32*528*256*2 = 8,650,752)

  prep_kernel<<<MBIG, 256, 0, stream>>>(fw, fb, aw, ab, Wc, bc);
  gemm_fused<<<NTB * MSB, 256, 0, stream>>>(x, Wc, bc, Yv);
  epi_kernel<<<BATCH * NCLU, 512, 0, stream>>>(Yv, ce, out);
}

// Round 3
// 245.847 us; speedup vs baseline: 1.1607x; 1.1607x over previous
//
#include <hip/hip_runtime.h>
#include <stdint.h>

typedef float f32x4 __attribute__((ext_vector_type(4)));
typedef __bf16 bf16x8 __attribute__((ext_vector_type(8)));
typedef unsigned short ushortx8 __attribute__((ext_vector_type(8)));

#define D_DIM 512
#define KGC 10
#define NCLU 8
#define BATCH 32
#define WPOS 250
#define WPAD 256
#define KDIM 3584   // 512*7
#define MROWS 522   // 512 feat + 10 assign
#define MPAD 528    // Y rows per batch
#define MBIG 576    // padded W rows (2 x 288)
#define MHB 288     // m-half rows per block (18 x 16)
#define BN 128
#define KSPLIT 4
#define KCHUNK 896  // KDIM / KSPLIT
#define NS 14       // KCHUNK / 64
#define NT 64       // n-tiles of 128 (N = 8192)

__device__ __forceinline__ float bf2f(unsigned short u) {
  union { unsigned int i; float f; } v; v.i = ((unsigned int)u) << 16; return v.f;
}
__device__ __forceinline__ unsigned short f2bf(float f) {
  union { float f; unsigned int i; } v; v.f = f;
  unsigned int r = v.i + 0x7FFFu + ((v.i >> 16) & 1u);
  return (unsigned short)(r >> 16);
}

__device__ __forceinline__ void load_lds16(const void* g, void* l) {
  __builtin_amdgcn_global_load_lds(
      (const __attribute__((address_space(1))) void*)g,
      (__attribute__((address_space(3))) void*)l, 16, 0, 0);
}

// ---------------- prep: Wcat(bf16) rows 0..575 = [feat_w ; assign_w ; zeros], bcat fp32 ----------------
__global__ void prep_kernel(const float* __restrict__ fw,
                            const float* __restrict__ fb,
                            const float* __restrict__ aw,
                            const float* __restrict__ ab,
                            unsigned short* __restrict__ Wcat,
                            float* __restrict__ bcat) {
  int r = blockIdx.x;
  unsigned short* dst = Wcat + (size_t)r * KDIM;
  const float* src = (r < D_DIM) ? (fw + (size_t)r * KDIM)
                   : (r < MROWS) ? (aw + (size_t)(r - D_DIM) * KDIM)
                                 : nullptr;
  for (int i = threadIdx.x; i < KDIM / 4; i += 256) {
    unsigned short o0 = 0, o1 = 0, o2 = 0, o3 = 0;
    if (src) {
      float4 v = ((const float4*)src)[i];
      o0 = f2bf(v.x); o1 = f2bf(v.y); o2 = f2bf(v.z); o3 = f2bf(v.w);
    }
    ushort4 o; o.x = o0; o.y = o1; o.z = o2; o.w = o3;
    ((ushort4*)dst)[i] = o;
  }
  if (threadIdx.x == 0)
    bcat[r] = r < D_DIM ? fb[r] : (r < MROWS ? ab[r - D_DIM] : 0.f);
}

// ---------------- fused GEMM: partial C[288m x 128n] over a K-quarter ------------------------------
// 512 thr, grid (64 nt, 2 mh, 4 sp) = 512 blocks = 2/CU. Single-buffer 2-barrier K-loop
// (the MEASURED-fastest schedule; dbuf regressed). Wave tiling 2m x 4n -> wave 144x32:
// per ks 9 A-frags + 2 B-frags feed 18 MFMA (was 17+1 for 17) => LDS reads -40%.
__global__ __launch_bounds__(512, 4) void gemm_fused(
    const float* __restrict__ x, const unsigned short* __restrict__ Wcat,
    float* __restrict__ P) {
  __shared__ __align__(16) unsigned short Wl[MHB * 64];  // 36,864 B swizzled
  __shared__ __align__(16) unsigned short Xl[BN * 64];   // 16,384 B swizzled
  const int tid = threadIdx.x;
  const int nt = blockIdx.x, mh = blockIdx.y, sp = blockIdx.z;
  const int lane = tid & 63, wv = tid >> 6;     // 8 waves
  const int wm = wv >> 2, wn = wv & 3;          // 2m x 4n
  const int fr = lane & 15, kg = lane >> 4;
  const int sx = fr & 7;
  const int nloc = tid & 127, oc = tid >> 7;    // staging: col nloc, octets oc & oc+4
  const int nglob = nt * BN + nloc;
  const int b = nglob >> 8, ncol = nglob & 255;
  const bool okn = ncol < WPOS;
  const float* xb = x + (size_t)b * KDIM * WPOS + ncol;
  const int kbase = sp * KCHUNK;
  const unsigned short* Wg = Wcat + (size_t)mh * MHB * KDIM + kbase;

  float xr[16];
  auto loadx = [&](int st) {
#pragma unroll
    for (int pass = 0; pass < 2; pass++) {
      int k0 = kbase + st * 64 + (oc + 4 * pass) * 8;
#pragma unroll
      for (int e = 0; e < 8; e++)
        xr[pass * 8 + e] = okn ? xb[(size_t)(k0 + e) * WPOS] : 0.f;
    }
  };

  f32x4 acc[9][2];
  const f32x4 zero = {0.f, 0.f, 0.f, 0.f};
#pragma unroll
  for (int f = 0; f < 9; f++) { acc[f][0] = zero; acc[f][1] = zero; }

  loadx(0);

  for (int st = 0; st < NS; st++) {
    __syncthreads();
    // W lds-dma: 288 rows x 8 octets = 2304 slots (4.5/thread)
#pragma unroll
    for (int it = 0; it < 5; it++) {
      int s = it * 512 + tid;
      if (s < MHB * 8) {
        int row = s >> 3, p = s & 7;
        int blk = p ^ (row & 7);
        load_lds16(Wg + (size_t)row * KDIM + st * 64 + blk * 8, &Wl[s * 8]);
      }
    }
    // commit X (loaded last iter), swizzled
#pragma unroll
    for (int pass = 0; pass < 2; pass++) {
      int oct = oc + 4 * pass;
      ushortx8 pk;
#pragma unroll
      for (int e = 0; e < 8; e++) pk[e] = f2bf(xr[pass * 8 + e]);
      *(ushortx8*)&Xl[nloc * 64 + (oct ^ (nloc & 7)) * 8] = pk;
    }
    __syncthreads();
    if (st + 1 < NS) loadx(st + 1);   // latency covered by MFMA loop
#pragma unroll
    for (int ks = 0; ks < 2; ks++) {
      const int off = ((ks * 4 + kg) ^ sx) * 8;
      bf16x8 b0 = *(const bf16x8*)&Xl[(wn * 32 + fr) * 64 + off];
      bf16x8 b1 = *(const bf16x8*)&Xl[(wn * 32 + 16 + fr) * 64 + off];
#pragma unroll
      for (int f = 0; f < 9; f++) {
        bf16x8 af = *(const bf16x8*)&Wl[(wm * 144 + f * 16 + fr) * 64 + off];
        acc[f][0] = __builtin_amdgcn_mfma_f32_16x16x32_bf16(af, b0, acc[f][0], 0, 0, 0);
        acc[f][1] = __builtin_amdgcn_mfma_f32_16x16x32_bf16(af, b1, acc[f][1], 0, 0, 0);
      }
    }
  }

  // store partials. C/D: col = lane&15 (n), row = kg*4 + r (m within frag)
  float* Pb = P + (size_t)(((sp * 2 + mh) * NT) + nt) * (MHB * BN);
#pragma unroll
  for (int f = 0; f < 9; f++) {
    const int m = wm * 144 + f * 16 + kg * 4;
#pragma unroll
    for (int nf = 0; nf < 2; nf++) {
      const int n = wn * 32 + nf * 16 + fr;
#pragma unroll
      for (int r = 0; r < 4; r++)
        Pb[(size_t)(m + r) * BN + n] = acc[f][nf][r];
    }
  }
}

// ---------------- reduce: Y[b][m][n](bf16) = relu_if_feat( sum_sp P + bias ) ----------------
// block = 16 m-rows x 16 n-octets (full 128 cols); grid (64 nt, 36 m-groups)
__global__ __launch_bounds__(256) void reduce_kernel(
    const float* __restrict__ P, const float* __restrict__ bcat,
    unsigned short* __restrict__ Y) {
  const int nt = blockIdx.x, mg = blockIdx.y;
  const int t = threadIdx.x;
  const int m = mg * 16 + (t >> 4);          // 0..575
  const int nl = (t & 15) * 8;               // n-octet within 128
  if (m >= MPAD) return;
  const int mh = m >= MHB, ml = m - mh * MHB;
  const size_t slice = (size_t)MHB * BN;
  const size_t base = (size_t)ml * BN + nl;
  float s[8];
#pragma unroll
  for (int e = 0; e < 8; e++) s[e] = 0.f;
#pragma unroll
  for (int sp = 0; sp < KSPLIT; sp++) {
    const float* p = P + ((size_t)((sp * 2 + mh) * NT) + nt) * slice + base;
    float4 a = *(const float4*)p;
    float4 c = *(const float4*)(p + 4);
    s[0] += a.x; s[1] += a.y; s[2] += a.z; s[3] += a.w;
    s[4] += c.x; s[5] += c.y; s[6] += c.z; s[7] += c.w;
  }
  float bias = bcat[m];
  ushortx8 o;
#pragma unroll
  for (int e = 0; e < 8; e++) {
    float v = s[e] + bias;
    if (m < D_DIM) v = fmaxf(v, 0.f);
    o[e] = f2bf(v);
  }
  const int nglob = nt * BN + nl;
  const int bb = nglob >> 8, col = nglob & 255;
  *(ushortx8*)&Y[(size_t)bb * MPAD * WPAD + (size_t)m * WPAD + col] = o;
}

// ---------------- epilogue: softmax, agg, subtract centroids*s_sum, L2-normalize ----------------
// 512 thr (8 waves, 1 d-row per thread), float4 broadcast soft reads,
// 8 independent accumulators to break the fma dependency chain.
__global__ __launch_bounds__(512) void epi_kernel(
    const unsigned short* __restrict__ Y, const float* __restrict__ cent,
    float* __restrict__ out) {
  __shared__ float soft[WPAD];
  __shared__ float red[8];
  const int b = blockIdx.x >> 3, k = blockIdx.x & 7;
  const int tid = threadIdx.x;
  const unsigned short* Yb = Y + (size_t)b * MPAD * WPAD;

  float sv = 0.f;
  if (tid < WPOS) {
    float lg[KGC];
    float mx = -1e30f;
#pragma unroll
    for (int j = 0; j < KGC; j++) {
      lg[j] = bf2f(Yb[(size_t)(D_DIM + j) * WPAD + tid]);
      mx = fmaxf(mx, lg[j]);
    }
    float s = 0.f, ek = 0.f;
#pragma unroll
    for (int j = 0; j < KGC; j++) {
      float e = __expf(lg[j] - mx);
      s += e;
      if (j == k) ek = e;
    }
    sv = ek / s;
  }
  if (tid < WPAD) soft[tid] = sv;   // tids 250..255 write 0
  __syncthreads();

  float v = sv;
#pragma unroll
  for (int o = 32; o > 0; o >>= 1) v += __shfl_down(v, o, 64);
  if ((tid & 63) == 0) red[tid >> 6] = v;
  __syncthreads();
  float ssum = 0.f;
#pragma unroll
  for (int i = 0; i < 8; i++) ssum += red[i];

  float a[8];
#pragma unroll
  for (int u = 0; u < 8; u++) a[u] = 0.f;
  const unsigned short* row = Yb + (size_t)tid * WPAD;
  for (int w = 0; w < WPAD; w += 8) {
    ushortx8 f0 = *(const ushortx8*)(row + w);
    float4 s0 = *(const float4*)&soft[w];
    float4 s1 = *(const float4*)&soft[w + 4];
    a[0] += bf2f(f0[0]) * s0.x;
    a[1] += bf2f(f0[1]) * s0.y;
    a[2] += bf2f(f0[2]) * s0.z;
    a[3] += bf2f(f0[3]) * s0.w;
    a[4] += bf2f(f0[4]) * s1.x;
    a[5] += bf2f(f0[5]) * s1.y;
    a[6] += bf2f(f0[6]) * s1.z;
    a[7] += bf2f(f0[7]) * s1.w;
  }
  float asum = ((a[0] + a[1]) + (a[2] + a[3])) + ((a[4] + a[5]) + (a[6] + a[7]));
  float c = asum - cent[(size_t)tid * KGC + k] * ssum;

  __syncthreads();
  float q = c * c;
#pragma unroll
  for (int o = 32; o > 0; o >>= 1) q += __shfl_down(q, o, 64);
  if ((tid & 63) == 0) red[tid >> 6] = q;
  __syncthreads();
  float nsum = 0.f;
#pragma unroll
  for (int i = 0; i < 8; i++) nsum += red[i];
  float norm = sqrtf(nsum);
  float inv = 1.f / fmaxf(norm, 1e-12f);

  float* ob = out + (size_t)b * (NCLU * D_DIM) + (size_t)k * D_DIM;
  ob[tid] = c * inv;
}

extern "C" void kernel_launch(void* const* d_in, const int* in_sizes, int n_in,
                              void* d_out, int out_size, void* d_ws, size_t ws_size,
                              hipStream_t stream) {
  const float* x  = (const float*)d_in[0];
  const float* fw = (const float*)d_in[1];
  const float* fb = (const float*)d_in[2];
  const float* aw = (const float*)d_in[3];
  const float* ab = (const float*)d_in[4];
  const float* ce = (const float*)d_in[5];
  float* out = (float*)d_out;
  char* ws = (char*)d_ws;

  const size_t WC_BYTES = (size_t)MBIG * KDIM * 2;                      //  4,128,768
  const size_t BC_BYTES = 4096;
  const size_t P_BYTES  = (size_t)KSPLIT * 2 * NT * MHB * BN * 4;       // 75,497,472
  unsigned short* Wc = (unsigned short*)(ws);
  float*          bc = (float*)(ws + WC_BYTES);
  float*          P  = (float*)(ws + WC_BYTES + BC_BYTES);
  unsigned short* Yv = (unsigned short*)(ws + WC_BYTES + BC_BYTES + P_BYTES);
  // total ws use ~88.3 MB

  prep_kernel<<<MBIG, 256, 0, stream>>>(fw, fb, aw, ab, Wc, bc);
  gemm_fused<<<dim3(NT, 2, KSPLIT), 512, 0, stream>>>(x, Wc, P);
  reduce_kernel<<<dim3(NT, 36), 256, 0, stream>>>(P, bc, Yv);
  epi_kernel<<<BATCH * NCLU, 512, 0, stream>>>(Yv, ce, out);
}